// Round 19
// baseline (183.464 us; speedup 1.0000x reference)
//
#include <hip/hip_runtime.h>

typedef __attribute__((ext_vector_type(8))) short short8;
typedef __attribute__((ext_vector_type(4))) float f32x4;

// ---------- bf16 helpers (bit manip, round-to-nearest-even) ----------
__device__ __forceinline__ float bf2f(unsigned u16) {
    union { float f; unsigned u32; } v; v.u32 = u16 << 16; return v.f;
}
__device__ __forceinline__ unsigned short f2bf(float f) {
    union { float f; unsigned u32; } v; v.f = f;
    unsigned x = v.u32;
    x += ((x >> 16) & 1u) + 0x7FFFu;
    return (unsigned short)(x >> 16);
}
__device__ __forceinline__ unsigned packbf(float a, float b) {
    return (unsigned)f2bf(a) | ((unsigned)f2bf(b) << 16);
}

// ---------------------------------------------------------------------
// kb12 v2 (wave-parallel): 32 blocks x 256 thr. Each (k,i) output pair is
// one 16-lane group: lane q covers c = q*8..q*8+7 (2 float4 loads each of
// W row / a1 / a2), then 4-step width-16 shuffle reduce. Kills the old
// 2-block serial 128-iter loop (~5-10 us of whole-GPU idle).
// ---------------------------------------------------------------------
__global__ __launch_bounds__(256) void kb12(const float* __restrict__ W,
                                            const float* __restrict__ a1,
                                            const float* __restrict__ a2,
                                            float* __restrict__ b1,
                                            float* __restrict__ b2) {
    const int t = threadIdx.x;
    const int grp = blockIdx.x * 16 + (t >> 4);     // [0, 512): (k,i) pair
    const int q = t & 15;
    const int k = grp >> 7, i = grp & 127;

    const float* wr = &W[k * 16384 + i * 128 + q * 8];
    const float* A1 = &a1[k * 128 + q * 8];
    const float* A2 = &a2[k * 128 + q * 8];
    float4 w0 = *(const float4*)wr;
    float4 w1 = *(const float4*)(wr + 4);
    float4 x0 = *(const float4*)A1;
    float4 x1 = *(const float4*)(A1 + 4);
    float4 y0 = *(const float4*)A2;
    float4 y1 = *(const float4*)(A2 + 4);
    float v1 = w0.x*x0.x + w0.y*x0.y + w0.z*x0.z + w0.w*x0.w
             + w1.x*x1.x + w1.y*x1.y + w1.z*x1.z + w1.w*x1.w;
    float v2 = w0.x*y0.x + w0.y*y0.y + w0.z*y0.z + w0.w*y0.w
             + w1.x*y1.x + w1.y*y1.y + w1.z*y1.z + w1.w*y1.w;
    #pragma unroll
    for (int m = 8; m >= 1; m >>= 1) {
        v1 += __shfl_xor(v1, m, 16);
        v2 += __shfl_xor(v2, m, 16);
    }
    if (q == 0) { b1[k * 128 + i] = v1; b2[k * 128 + i] = v2; }
}

// ---------------------------------------------------------------------
// kscore: blocks [0,256) = Wt/W0t transposes (consumed by k4 two launches
// later -> fully hidden). Blocks [256,..): 4 nodes/wave, 16 lanes/node;
// width-16 butterflies shared across nodes. Outputs: hb(bf16), s1, s2, g.
// ---------------------------------------------------------------------
__global__ __launch_bounds__(256) void kscore(const float* __restrict__ h,
                                              const float* __restrict__ Wg,
                                              const float* __restrict__ b1,
                                              const float* __restrict__ b2,
                                              const float* __restrict__ W,
                                              const float* __restrict__ W0,
                                              unsigned* __restrict__ hb32,
                                              float* __restrict__ s1,
                                              float* __restrict__ s2,
                                              float* __restrict__ g,
                                              unsigned short* __restrict__ Wt,
                                              unsigned short* __restrict__ W0t,
                                              int N) {
    const int b = blockIdx.x, t = threadIdx.x;
    if (b < 256) {
        #pragma unroll
        for (int e = 0; e < 2; ++e) {
            int i = b * 512 + e * 256 + t;          // [0, 131072)
            if (i < 65536) {
                int head = i >> 14, rem = i & 16383, k = rem >> 7, col = rem & 127;
                Wt[head * 16384 + col * 128 + k] = f2bf(W[i]);
            } else {
                int i2 = i - 65536;
                int k = i2 >> 7, col = i2 & 127;
                W0t[col * 512 + k] = f2bf(W0[i2]);
            }
        }
        return;
    }
    const int w = t >> 6, l = t & 63;
    const int grp = l >> 4, q = l & 15;
    const int n = (b - 256) * 16 + w * 4 + grp;
    if (n >= N) return;

    float4 hv0 = *(const float4*)&h[(size_t)n * 128 + q * 8];
    float4 hv1 = *(const float4*)&h[(size_t)n * 128 + q * 8 + 4];
    float ha[8] = {hv0.x, hv0.y, hv0.z, hv0.w, hv1.x, hv1.y, hv1.z, hv1.w};

    uint4 hbv;
    hbv.x = packbf(ha[0], ha[1]); hbv.y = packbf(ha[2], ha[3]);
    hbv.z = packbf(ha[4], ha[5]); hbv.w = packbf(ha[6], ha[7]);
    *(uint4*)&hb32[(size_t)n * 64 + q * 4] = hbv;

    float p[12];
    #pragma unroll
    for (int k = 0; k < 4; ++k) {
        float4 ba = *(const float4*)&b1[k * 128 + q * 8];
        float4 bb = *(const float4*)&b1[k * 128 + q * 8 + 4];
        p[k] = ha[0]*ba.x + ha[1]*ba.y + ha[2]*ba.z + ha[3]*ba.w
             + ha[4]*bb.x + ha[5]*bb.y + ha[6]*bb.z + ha[7]*bb.w;
        float4 ca = *(const float4*)&b2[k * 128 + q * 8];
        float4 cb = *(const float4*)&b2[k * 128 + q * 8 + 4];
        p[4+k] = ha[0]*ca.x + ha[1]*ca.y + ha[2]*ca.z + ha[3]*ca.w
               + ha[4]*cb.x + ha[5]*cb.y + ha[6]*cb.z + ha[7]*cb.w;
    }
    p[8] = p[9] = p[10] = p[11] = 0.f;
    #pragma unroll
    for (int e = 0; e < 8; ++e) {
        float4 wg = *(const float4*)&Wg[(q * 8 + e) * 4];
        p[8]  += ha[e] * wg.x;
        p[9]  += ha[e] * wg.y;
        p[10] += ha[e] * wg.z;
        p[11] += ha[e] * wg.w;
    }
    #pragma unroll
    for (int m = 8; m >= 1; m >>= 1) {
        #pragma unroll
        for (int i = 0; i < 12; ++i) p[i] += __shfl_xor(p[i], m, 16);
    }
    if (q == 0) {
        *(float4*)&s1[n * 4] = make_float4(p[0], p[1], p[2], p[3]);
        *(float4*)&s2[n * 4] = make_float4(p[4], p[5], p[6], p[7]);
        float mx = fmaxf(fmaxf(p[8], p[9]), fmaxf(p[10], p[11]));
        float e0 = __expf(p[8] - mx), e1 = __expf(p[9] - mx);
        float e2 = __expf(p[10] - mx), e3 = __expf(p[11] - mx);
        float si = 1.f / (e0 + e1 + e2 + e3);
        *(float4*)&g[n * 4] = make_float4(e0 * si, e1 * si, e2 * si, e3 * si);
    }
}

// ---------------------------------------------------------------------
// k3_mix (round-10 gather, + occupancy hint): one node per wave (4/block).
// __launch_bounds__(256, 8) -> min 8 waves/EU = 8 blocks/CU (VGPR cap 64,
// we use 40 -> no spill). Scores + softmax (att -> LDS float4), then
// gather h_bf16[j] (256 B/row) with scalar FMAs. No barriers.
// ---------------------------------------------------------------------
__global__ __launch_bounds__(256, 8) void k3_mix(const int* __restrict__ idx,
                                                 const unsigned* __restrict__ hb32,
                                                 const float* __restrict__ s1,
                                                 const float* __restrict__ s2,
                                                 unsigned* __restrict__ Mx32,
                                                 int N) {
    __shared__ float att4s[4][32][4];
    const int t = threadIdx.x, w = t >> 6, l = t & 63;
    const int d = l & 31, half = l >> 5;
    int n = blockIdx.x * 4 + w;
    const bool valid = (n < N);
    if (!valid) n = N - 1;

    // scores + softmax: lane (half,d) handles heads {2*half, 2*half+1}
    int j = idx[(size_t)n * 32 + d];
    float2 s2v = *(const float2*)&s2[(size_t)j * 4 + half * 2];
    const float* s1p = &s1[(size_t)n * 4];
    float e0 = s1p[half * 2] + s2v.x;
    float e1 = s1p[half * 2 + 1] + s2v.y;
    e0 = (e0 >= 0.f) ? e0 : 0.01f * e0;
    e1 = (e1 >= 0.f) ? e1 : 0.01f * e1;
    float m0 = e0, m1 = e1;
    #pragma unroll
    for (int mm = 16; mm >= 1; mm >>= 1) {
        m0 = fmaxf(m0, __shfl_xor(m0, mm, 32));
        m1 = fmaxf(m1, __shfl_xor(m1, mm, 32));
    }
    float p0 = __expf(e0 - m0), p1 = __expf(e1 - m1);
    float q0 = p0, q1 = p1;
    #pragma unroll
    for (int mm = 16; mm >= 1; mm >>= 1) {
        q0 += __shfl_xor(q0, mm, 32);
        q1 += __shfl_xor(q1, mm, 32);
    }
    *(float2*)&att4s[w][d][half * 2] = make_float2(p0 / q0, p1 / q1);

    // gather h rows, accumulate 4-head weighted sums; lane owns cols {2l,2l+1}
    float ac[4][2] = {};
    #pragma unroll
    for (int dd = 0; dd < 32; ++dd) {
        int jj = __shfl(j, dd, 64);
        unsigned hv = hb32[(size_t)jj * 64 + l];
        float h0 = bf2f(hv & 0xffffu);
        float h1 = bf2f(hv >> 16);
        float4 a4 = *(const float4*)&att4s[w][dd][0];
        ac[0][0] += a4.x * h0; ac[0][1] += a4.x * h1;
        ac[1][0] += a4.y * h0; ac[1][1] += a4.y * h1;
        ac[2][0] += a4.z * h0; ac[2][1] += a4.z * h1;
        ac[3][0] += a4.w * h0; ac[3][1] += a4.w * h1;
    }
    if (valid) {
        #pragma unroll
        for (int k = 0; k < 4; ++k)
            Mx32[(size_t)n * 256 + k * 64 + l] = packbf(ac[k][0], ac[k][1]);
    }
}

// ---------------------------------------------------------------------
// k4_gemm v10 (round-18): persistent, 512 thr, __launch_bounds__(512,2).
// Resident B panels bf1 (head w&3, col-half w>>2) + bf2 (col-group w).
// Single Uin with stage-into-dead-buffer:
//   ph1 | sync | STAGE(t+P)->Uin || ph2(Uout, dual chains) | sync
// ---------------------------------------------------------------------
typedef const __attribute__((address_space(1))) char gbyte;
typedef __attribute__((address_space(3))) char lbyte;

__global__ __launch_bounds__(512, 2) void k4_gemm(const unsigned short* __restrict__ Mx,
                                                  const unsigned short* __restrict__ Wt,
                                                  const unsigned short* __restrict__ W0t,
                                                  const float* __restrict__ g,
                                                  float* __restrict__ out,
                                                  int N, int T) {
    __shared__ unsigned short Uin[32 * 512];    // 32 KB
    __shared__ unsigned short Uout[32 * 512];   // 32 KB
    __shared__ float gld[128];                  // 0.5 KB
    const int tid = threadIdx.x, w = tid >> 6, l = tid & 63;
    const int l15 = l & 15, lh = l >> 4;
    const int hd = w & 3, ch = w >> 2;
    const int P = gridDim.x;

    // resident B panels: 64 + 64 VGPR
    short8 bf1[4][4];
    #pragma unroll
    for (int s = 0; s < 4; ++s)
        #pragma unroll
        for (int c = 0; c < 4; ++c)
            bf1[s][c] = *(const short8*)&Wt[(size_t)hd * 16384 +
                                            (size_t)((ch * 4 + c) * 16 + l15) * 128 + s * 32 + lh * 8];
    short8 bf2[16];
    #pragma unroll
    for (int ks = 0; ks < 16; ++ks)
        bf2[ks] = *(const short8*)&W0t[(size_t)(w * 16 + l15) * 512 + ks * 32 + lh * 8];

    const int t0 = blockIdx.x;

    auto STAGE = [&](int tile) {
        const size_t n0 = (size_t)tile * 32;
        if (w == 0 && l < 32) {                      // gate rows: 32 x 16 B
            size_t n = n0 + l; if (n >= (size_t)N) n = N - 1;
            __builtin_amdgcn_global_load_lds((gbyte*)((const char*)g + n * 16),
                                             (lbyte*)&gld[0], 16, 0, 0);
        }
        #pragma unroll
        for (int p = 0; p < 4; ++p) {
            int r = p * 8 + w;                       // one wave covers one 1024B row
            size_t n = n0 + r;
            if (n >= (size_t)N) n = N - 1;           // clamp (pad rows discarded later)
            // pre-swizzled global source; linear LDS dest (wave-uniform base)
            const char* src = (const char*)Mx + n * 1024 + ((l * 16) ^ ((r & 7) << 4));
            __builtin_amdgcn_global_load_lds((gbyte*)src, (lbyte*)&Uin[r * 512], 16, 0, 0);
        }
    };

    STAGE(t0);
    __syncthreads();                                 // tile-0 staged

    for (int t = t0; t < T; t += P) {
        const int n0 = t * 32;

        // ---- phase 1: Uout = relu(Uin @ W_hd) * g, cols (hd,ch) ----
        const char* Uib = (const char*)Uin;
        #pragma unroll
        for (int rg = 0; rg < 2; ++rg) {
            const int arow = rg * 16 + l15;
            short8 af[4];
            #pragma unroll
            for (int s = 0; s < 4; ++s) {
                int ab = arow * 1024 + hd * 256 + s * 64 + lh * 16;
                af[s] = *(const short8*)(Uib + (ab ^ ((arow & 7) << 4)));
            }
            f32x4 acc[4] = {};
            #pragma unroll
            for (int s = 0; s < 4; ++s)
                #pragma unroll
                for (int c = 0; c < 4; ++c)
                    acc[c] = __builtin_amdgcn_mfma_f32_16x16x32_bf16(af[s], bf1[s][c], acc[c], 0, 0, 0);
            #pragma unroll
            for (int c = 0; c < 4; ++c) {
                const int col = hd * 128 + (ch * 4 + c) * 16 + l15;
                #pragma unroll
                for (int r = 0; r < 4; ++r) {
                    int row = rg * 16 + lh * 4 + r;
                    float v = fmaxf(acc[c][r], 0.f) * gld[row * 4 + hd];
                    int ub = row * 1024 + col * 2;
                    *(unsigned short*)((char*)Uout + (ub ^ ((row & 7) << 4))) = f2bf(v);
                }
            }
        }

        __syncthreads();     // ph1 done everywhere: Uout visible, Uin & gld dead

        if (t + P < T) STAGE(t + P);    // stage next tile into Uin; overlaps ph2

        // ---- phase 2: out = Uout @ W0t; wave w -> col-group w ----
        const char* Uob = (const char*)Uout;
        #pragma unroll
        for (int rg = 0; rg < 2; ++rg) {
            const int arow = rg * 16 + l15;
            f32x4 oaccA = {}, oaccB = {};
            #pragma unroll
            for (int ks = 0; ks < 16; ks += 2) {
                int abA = arow * 1024 + ks * 64 + lh * 16;
                int abB = abA + 64;
                short8 afrA = *(const short8*)(Uob + (abA ^ ((arow & 7) << 4)));
                short8 afrB = *(const short8*)(Uob + (abB ^ ((arow & 7) << 4)));
                oaccA = __builtin_amdgcn_mfma_f32_16x16x32_bf16(afrA, bf2[ks], oaccA, 0, 0, 0);
                oaccB = __builtin_amdgcn_mfma_f32_16x16x32_bf16(afrB, bf2[ks + 1], oaccB, 0, 0, 0);
            }
            f32x4 oacc = oaccA + oaccB;
            #pragma unroll
            for (int r = 0; r < 4; ++r) {
                int n = n0 + rg * 16 + lh * 4 + r;
                if (n < N) out[(size_t)n * 128 + w * 16 + l15] = oacc[r];
            }
        }

        __syncthreads();     // drains stage (vmcnt) + all ph2 reads of Uout done
    }
}

// ---------------------------------------------------------------------
extern "C" void kernel_launch(void* const* d_in, const int* in_sizes, int n_in,
                              void* d_out, int out_size, void* d_ws, size_t ws_size,
                              hipStream_t stream) {
    const float* h     = (const float*)d_in[0];
    const int*   neigh = (const int*)d_in[1];
    const float* W     = (const float*)d_in[2];
    const float* a1    = (const float*)d_in[3];
    const float* a2    = (const float*)d_in[4];
    const float* Wg    = (const float*)d_in[5];
    const float* W0    = (const float*)d_in[6];
    float* out = (float*)d_out;

    const int N = in_sizes[0] / 128;

    char* ws = (char*)d_ws;
    unsigned* hb32 = (unsigned*)ws;                                  // N*64 u32 (h bf16)
    unsigned* Mx32 = (unsigned*)(ws + (size_t)N * 256);              // N*256 u32 (Mixed bf16)
    float* s1 = (float*)(ws + (size_t)N * 256 + (size_t)N * 1024);   // N*4 f32
    float* s2 = s1 + (size_t)N * 4;
    float* g  = s2 + (size_t)N * 4;
    unsigned short* Wt  = (unsigned short*)(g + (size_t)N * 4);      // 128 KB
    unsigned short* W0t = Wt + 65536;                                // 128 KB
    float* b1 = (float*)(W0t + 65536);                               // 2 KB
    float* b2 = b1 + 512;                                            // 2 KB

    const int T = (N + 31) / 32;
    const int P = (T < 256) ? T : 256;

    kb12<<<dim3(32), dim3(256), 0, stream>>>(W, a1, a2, b1, b2);
    kscore<<<dim3((N + 15) / 16 + 256), dim3(256), 0, stream>>>(h, Wg, b1, b2, W, W0,
                                                                hb32, s1, s2, g, Wt, W0t, N);
    k3_mix<<<dim3((N + 3) / 4), dim3(256), 0, stream>>>(neigh, hb32, s1, s2, Mx32, N);
    k4_gemm<<<dim3(P), dim3(512), 0, stream>>>((const unsigned short*)Mx32, Wt, W0t, g,
                                               out, N, T);
}

// Round 20
// 117.962 us; speedup vs baseline: 1.5553x; 1.5553x over previous
//
#include <hip/hip_runtime.h>

typedef __attribute__((ext_vector_type(8))) short short8;
typedef __attribute__((ext_vector_type(4))) float f32x4;

// ---------- bf16 helpers (bit manip, round-to-nearest-even) ----------
__device__ __forceinline__ float bf2f(unsigned u16) {
    union { float f; unsigned u32; } v; v.u32 = u16 << 16; return v.f;
}
__device__ __forceinline__ unsigned short f2bf(float f) {
    union { float f; unsigned u32; } v; v.f = f;
    unsigned x = v.u32;
    x += ((x >> 16) & 1u) + 0x7FFFu;
    return (unsigned short)(x >> 16);
}
__device__ __forceinline__ unsigned packbf(float a, float b) {
    return (unsigned)f2bf(a) | ((unsigned)f2bf(b) << 16);
}

// ---------------------------------------------------------------------
// kb12 v2 (wave-parallel): 32 blocks x 256 thr. Each (k,i) output pair is
// one 16-lane group; 4-step width-16 shuffle reduce.
// ---------------------------------------------------------------------
__global__ __launch_bounds__(256) void kb12(const float* __restrict__ W,
                                            const float* __restrict__ a1,
                                            const float* __restrict__ a2,
                                            float* __restrict__ b1,
                                            float* __restrict__ b2) {
    const int t = threadIdx.x;
    const int grp = blockIdx.x * 16 + (t >> 4);     // [0, 512): (k,i) pair
    const int q = t & 15;
    const int k = grp >> 7, i = grp & 127;

    const float* wr = &W[k * 16384 + i * 128 + q * 8];
    const float* A1 = &a1[k * 128 + q * 8];
    const float* A2 = &a2[k * 128 + q * 8];
    float4 w0 = *(const float4*)wr;
    float4 w1 = *(const float4*)(wr + 4);
    float4 x0 = *(const float4*)A1;
    float4 x1 = *(const float4*)(A1 + 4);
    float4 y0 = *(const float4*)A2;
    float4 y1 = *(const float4*)(A2 + 4);
    float v1 = w0.x*x0.x + w0.y*x0.y + w0.z*x0.z + w0.w*x0.w
             + w1.x*x1.x + w1.y*x1.y + w1.z*x1.z + w1.w*x1.w;
    float v2 = w0.x*y0.x + w0.y*y0.y + w0.z*y0.z + w0.w*y0.w
             + w1.x*y1.x + w1.y*y1.y + w1.z*y1.z + w1.w*y1.w;
    #pragma unroll
    for (int m = 8; m >= 1; m >>= 1) {
        v1 += __shfl_xor(v1, m, 16);
        v2 += __shfl_xor(v2, m, 16);
    }
    if (q == 0) { b1[k * 128 + i] = v1; b2[k * 128 + i] = v2; }
}

// ---------------------------------------------------------------------
// kscore: blocks [0,256) = Wt/W0t transposes (consumed by k4 two launches
// later -> fully hidden). Blocks [256,..): 4 nodes/wave, 16 lanes/node;
// width-16 butterflies shared across nodes. Outputs: hb(bf16), s1, s2, g.
// ---------------------------------------------------------------------
__global__ __launch_bounds__(256) void kscore(const float* __restrict__ h,
                                              const float* __restrict__ Wg,
                                              const float* __restrict__ b1,
                                              const float* __restrict__ b2,
                                              const float* __restrict__ W,
                                              const float* __restrict__ W0,
                                              unsigned* __restrict__ hb32,
                                              float* __restrict__ s1,
                                              float* __restrict__ s2,
                                              float* __restrict__ g,
                                              unsigned short* __restrict__ Wt,
                                              unsigned short* __restrict__ W0t,
                                              int N) {
    const int b = blockIdx.x, t = threadIdx.x;
    if (b < 256) {
        #pragma unroll
        for (int e = 0; e < 2; ++e) {
            int i = b * 512 + e * 256 + t;          // [0, 131072)
            if (i < 65536) {
                int head = i >> 14, rem = i & 16383, k = rem >> 7, col = rem & 127;
                Wt[head * 16384 + col * 128 + k] = f2bf(W[i]);
            } else {
                int i2 = i - 65536;
                int k = i2 >> 7, col = i2 & 127;
                W0t[col * 512 + k] = f2bf(W0[i2]);
            }
        }
        return;
    }
    const int w = t >> 6, l = t & 63;
    const int grp = l >> 4, q = l & 15;
    const int n = (b - 256) * 16 + w * 4 + grp;
    if (n >= N) return;

    float4 hv0 = *(const float4*)&h[(size_t)n * 128 + q * 8];
    float4 hv1 = *(const float4*)&h[(size_t)n * 128 + q * 8 + 4];
    float ha[8] = {hv0.x, hv0.y, hv0.z, hv0.w, hv1.x, hv1.y, hv1.z, hv1.w};

    uint4 hbv;
    hbv.x = packbf(ha[0], ha[1]); hbv.y = packbf(ha[2], ha[3]);
    hbv.z = packbf(ha[4], ha[5]); hbv.w = packbf(ha[6], ha[7]);
    *(uint4*)&hb32[(size_t)n * 64 + q * 4] = hbv;

    float p[12];
    #pragma unroll
    for (int k = 0; k < 4; ++k) {
        float4 ba = *(const float4*)&b1[k * 128 + q * 8];
        float4 bb = *(const float4*)&b1[k * 128 + q * 8 + 4];
        p[k] = ha[0]*ba.x + ha[1]*ba.y + ha[2]*ba.z + ha[3]*ba.w
             + ha[4]*bb.x + ha[5]*bb.y + ha[6]*bb.z + ha[7]*bb.w;
        float4 ca = *(const float4*)&b2[k * 128 + q * 8];
        float4 cb = *(const float4*)&b2[k * 128 + q * 8 + 4];
        p[4+k] = ha[0]*ca.x + ha[1]*ca.y + ha[2]*ca.z + ha[3]*ca.w
               + ha[4]*cb.x + ha[5]*cb.y + ha[6]*cb.z + ha[7]*cb.w;
    }
    p[8] = p[9] = p[10] = p[11] = 0.f;
    #pragma unroll
    for (int e = 0; e < 8; ++e) {
        float4 wg = *(const float4*)&Wg[(q * 8 + e) * 4];
        p[8]  += ha[e] * wg.x;
        p[9]  += ha[e] * wg.y;
        p[10] += ha[e] * wg.z;
        p[11] += ha[e] * wg.w;
    }
    #pragma unroll
    for (int m = 8; m >= 1; m >>= 1) {
        #pragma unroll
        for (int i = 0; i < 12; ++i) p[i] += __shfl_xor(p[i], m, 16);
    }
    if (q == 0) {
        *(float4*)&s1[n * 4] = make_float4(p[0], p[1], p[2], p[3]);
        *(float4*)&s2[n * 4] = make_float4(p[4], p[5], p[6], p[7]);
        float mx = fmaxf(fmaxf(p[8], p[9]), fmaxf(p[10], p[11]));
        float e0 = __expf(p[8] - mx), e1 = __expf(p[9] - mx);
        float e2 = __expf(p[10] - mx), e3 = __expf(p[11] - mx);
        float si = 1.f / (e0 + e1 + e2 + e3);
        *(float4*)&g[n * 4] = make_float4(e0 * si, e1 * si, e2 * si, e3 * si);
    }
}

// ---------------------------------------------------------------------
// k3_mix (round-10 proven best, PLAIN launch bounds): one node per wave
// (4/block, 256 thr). NOTE: do NOT add a min-waves occupancy hint — r19
// showed (256,8) caps VGPR at 32 (<40 needed) and spills (57->122 us).
// Scores + softmax (att -> LDS float4 per neighbor), then gather
// h_bf16[j] (256 B/row) with scalar FMAs. No barriers.
// ---------------------------------------------------------------------
__global__ __launch_bounds__(256) void k3_mix(const int* __restrict__ idx,
                                              const unsigned* __restrict__ hb32,
                                              const float* __restrict__ s1,
                                              const float* __restrict__ s2,
                                              unsigned* __restrict__ Mx32,
                                              int N) {
    __shared__ float att4s[4][32][4];
    const int t = threadIdx.x, w = t >> 6, l = t & 63;
    const int d = l & 31, half = l >> 5;
    int n = blockIdx.x * 4 + w;
    const bool valid = (n < N);
    if (!valid) n = N - 1;

    // scores + softmax: lane (half,d) handles heads {2*half, 2*half+1}
    int j = idx[(size_t)n * 32 + d];
    float2 s2v = *(const float2*)&s2[(size_t)j * 4 + half * 2];
    const float* s1p = &s1[(size_t)n * 4];
    float e0 = s1p[half * 2] + s2v.x;
    float e1 = s1p[half * 2 + 1] + s2v.y;
    e0 = (e0 >= 0.f) ? e0 : 0.01f * e0;
    e1 = (e1 >= 0.f) ? e1 : 0.01f * e1;
    float m0 = e0, m1 = e1;
    #pragma unroll
    for (int mm = 16; mm >= 1; mm >>= 1) {
        m0 = fmaxf(m0, __shfl_xor(m0, mm, 32));
        m1 = fmaxf(m1, __shfl_xor(m1, mm, 32));
    }
    float p0 = __expf(e0 - m0), p1 = __expf(e1 - m1);
    float q0 = p0, q1 = p1;
    #pragma unroll
    for (int mm = 16; mm >= 1; mm >>= 1) {
        q0 += __shfl_xor(q0, mm, 32);
        q1 += __shfl_xor(q1, mm, 32);
    }
    *(float2*)&att4s[w][d][half * 2] = make_float2(p0 / q0, p1 / q1);

    // gather h rows, accumulate 4-head weighted sums; lane owns cols {2l,2l+1}
    float ac[4][2] = {};
    #pragma unroll
    for (int dd = 0; dd < 32; ++dd) {
        int jj = __shfl(j, dd, 64);
        unsigned hv = hb32[(size_t)jj * 64 + l];
        float h0 = bf2f(hv & 0xffffu);
        float h1 = bf2f(hv >> 16);
        float4 a4 = *(const float4*)&att4s[w][dd][0];
        ac[0][0] += a4.x * h0; ac[0][1] += a4.x * h1;
        ac[1][0] += a4.y * h0; ac[1][1] += a4.y * h1;
        ac[2][0] += a4.z * h0; ac[2][1] += a4.z * h1;
        ac[3][0] += a4.w * h0; ac[3][1] += a4.w * h1;
    }
    if (valid) {
        #pragma unroll
        for (int k = 0; k < 4; ++k)
            Mx32[(size_t)n * 256 + k * 64 + l] = packbf(ac[k][0], ac[k][1]);
    }
}

// ---------------------------------------------------------------------
// k4_gemm v10 (round-18): persistent, 512 thr, __launch_bounds__(512,2).
// Resident B panels bf1 (head w&3, col-half w>>2) + bf2 (col-group w).
// Single Uin with stage-into-dead-buffer:
//   ph1 | sync | STAGE(t+P)->Uin || ph2(Uout, dual chains) | sync
// ---------------------------------------------------------------------
typedef const __attribute__((address_space(1))) char gbyte;
typedef __attribute__((address_space(3))) char lbyte;

__global__ __launch_bounds__(512, 2) void k4_gemm(const unsigned short* __restrict__ Mx,
                                                  const unsigned short* __restrict__ Wt,
                                                  const unsigned short* __restrict__ W0t,
                                                  const float* __restrict__ g,
                                                  float* __restrict__ out,
                                                  int N, int T) {
    __shared__ unsigned short Uin[32 * 512];    // 32 KB
    __shared__ unsigned short Uout[32 * 512];   // 32 KB
    __shared__ float gld[128];                  // 0.5 KB
    const int tid = threadIdx.x, w = tid >> 6, l = tid & 63;
    const int l15 = l & 15, lh = l >> 4;
    const int hd = w & 3, ch = w >> 2;
    const int P = gridDim.x;

    // resident B panels: 64 + 64 VGPR
    short8 bf1[4][4];
    #pragma unroll
    for (int s = 0; s < 4; ++s)
        #pragma unroll
        for (int c = 0; c < 4; ++c)
            bf1[s][c] = *(const short8*)&Wt[(size_t)hd * 16384 +
                                            (size_t)((ch * 4 + c) * 16 + l15) * 128 + s * 32 + lh * 8];
    short8 bf2[16];
    #pragma unroll
    for (int ks = 0; ks < 16; ++ks)
        bf2[ks] = *(const short8*)&W0t[(size_t)(w * 16 + l15) * 512 + ks * 32 + lh * 8];

    const int t0 = blockIdx.x;

    auto STAGE = [&](int tile) {
        const size_t n0 = (size_t)tile * 32;
        if (w == 0 && l < 32) {                      // gate rows: 32 x 16 B
            size_t n = n0 + l; if (n >= (size_t)N) n = N - 1;
            __builtin_amdgcn_global_load_lds((gbyte*)((const char*)g + n * 16),
                                             (lbyte*)&gld[0], 16, 0, 0);
        }
        #pragma unroll
        for (int p = 0; p < 4; ++p) {
            int r = p * 8 + w;                       // one wave covers one 1024B row
            size_t n = n0 + r;
            if (n >= (size_t)N) n = N - 1;           // clamp (pad rows discarded later)
            // pre-swizzled global source; linear LDS dest (wave-uniform base)
            const char* src = (const char*)Mx + n * 1024 + ((l * 16) ^ ((r & 7) << 4));
            __builtin_amdgcn_global_load_lds((gbyte*)src, (lbyte*)&Uin[r * 512], 16, 0, 0);
        }
    };

    STAGE(t0);
    __syncthreads();                                 // tile-0 staged

    for (int t = t0; t < T; t += P) {
        const int n0 = t * 32;

        // ---- phase 1: Uout = relu(Uin @ W_hd) * g, cols (hd,ch) ----
        const char* Uib = (const char*)Uin;
        #pragma unroll
        for (int rg = 0; rg < 2; ++rg) {
            const int arow = rg * 16 + l15;
            short8 af[4];
            #pragma unroll
            for (int s = 0; s < 4; ++s) {
                int ab = arow * 1024 + hd * 256 + s * 64 + lh * 16;
                af[s] = *(const short8*)(Uib + (ab ^ ((arow & 7) << 4)));
            }
            f32x4 acc[4] = {};
            #pragma unroll
            for (int s = 0; s < 4; ++s)
                #pragma unroll
                for (int c = 0; c < 4; ++c)
                    acc[c] = __builtin_amdgcn_mfma_f32_16x16x32_bf16(af[s], bf1[s][c], acc[c], 0, 0, 0);
            #pragma unroll
            for (int c = 0; c < 4; ++c) {
                const int col = hd * 128 + (ch * 4 + c) * 16 + l15;
                #pragma unroll
                for (int r = 0; r < 4; ++r) {
                    int row = rg * 16 + lh * 4 + r;
                    float v = fmaxf(acc[c][r], 0.f) * gld[row * 4 + hd];
                    int ub = row * 1024 + col * 2;
                    *(unsigned short*)((char*)Uout + (ub ^ ((row & 7) << 4))) = f2bf(v);
                }
            }
        }

        __syncthreads();     // ph1 done everywhere: Uout visible, Uin & gld dead

        if (t + P < T) STAGE(t + P);    // stage next tile into Uin; overlaps ph2

        // ---- phase 2: out = Uout @ W0t; wave w -> col-group w ----
        const char* Uob = (const char*)Uout;
        #pragma unroll
        for (int rg = 0; rg < 2; ++rg) {
            const int arow = rg * 16 + l15;
            f32x4 oaccA = {}, oaccB = {};
            #pragma unroll
            for (int ks = 0; ks < 16; ks += 2) {
                int abA = arow * 1024 + ks * 64 + lh * 16;
                int abB = abA + 64;
                short8 afrA = *(const short8*)(Uob + (abA ^ ((arow & 7) << 4)));
                short8 afrB = *(const short8*)(Uob + (abB ^ ((arow & 7) << 4)));
                oaccA = __builtin_amdgcn_mfma_f32_16x16x32_bf16(afrA, bf2[ks], oaccA, 0, 0, 0);
                oaccB = __builtin_amdgcn_mfma_f32_16x16x32_bf16(afrB, bf2[ks + 1], oaccB, 0, 0, 0);
            }
            f32x4 oacc = oaccA + oaccB;
            #pragma unroll
            for (int r = 0; r < 4; ++r) {
                int n = n0 + rg * 16 + lh * 4 + r;
                if (n < N) out[(size_t)n * 128 + w * 16 + l15] = oacc[r];
            }
        }

        __syncthreads();     // drains stage (vmcnt) + all ph2 reads of Uout done
    }
}

// ---------------------------------------------------------------------
extern "C" void kernel_launch(void* const* d_in, const int* in_sizes, int n_in,
                              void* d_out, int out_size, void* d_ws, size_t ws_size,
                              hipStream_t stream) {
    const float* h     = (const float*)d_in[0];
    const int*   neigh = (const int*)d_in[1];
    const float* W     = (const float*)d_in[2];
    const float* a1    = (const float*)d_in[3];
    const float* a2    = (const float*)d_in[4];
    const float* Wg    = (const float*)d_in[5];
    const float* W0    = (const float*)d_in[6];
    float* out = (float*)d_out;

    const int N = in_sizes[0] / 128;

    char* ws = (char*)d_ws;
    unsigned* hb32 = (unsigned*)ws;                                  // N*64 u32 (h bf16)
    unsigned* Mx32 = (unsigned*)(ws + (size_t)N * 256);              // N*256 u32 (Mixed bf16)
    float* s1 = (float*)(ws + (size_t)N * 256 + (size_t)N * 1024);   // N*4 f32
    float* s2 = s1 + (size_t)N * 4;
    float* g  = s2 + (size_t)N * 4;
    unsigned short* Wt  = (unsigned short*)(g + (size_t)N * 4);      // 128 KB
    unsigned short* W0t = Wt + 65536;                                // 128 KB
    float* b1 = (float*)(W0t + 65536);                               // 2 KB
    float* b2 = b1 + 512;                                            // 2 KB

    const int T = (N + 31) / 32;
    const int P = (T < 256) ? T : 256;

    kb12<<<dim3(32), dim3(256), 0, stream>>>(W, a1, a2, b1, b2);
    kscore<<<dim3((N + 15) / 16 + 256), dim3(256), 0, stream>>>(h, Wg, b1, b2, W, W0,
                                                                hb32, s1, s2, g, Wt, W0t, N);
    k3_mix<<<dim3((N + 3) / 4), dim3(256), 0, stream>>>(neigh, hb32, s1, s2, Mx32, N);
    k4_gemm<<<dim3(P), dim3(512), 0, stream>>>((const unsigned short*)Mx32, Wt, W0t, g,
                                               out, N, T);
}